// Round 3
// baseline (144.241 us; speedup 1.0000x reference)
//
#include <hip/hip_runtime.h>

#define NSEG 128
#define SSTEPS 32
#define TDIM 32
#define TILE 512          // nodes staged to LDS per tile

// ---------------- Kernel A: segment offsets via binary search ---------------
__global__ void seg_offsets_kernel(const int* __restrict__ idx32, int n,
                                   int* __restrict__ offsets) {
    int b = threadIdx.x;
    if (b > NSEG) return;
    bool is64 = (idx32[n - 1] == 0);   // int64 high word of last element
    if (b == NSEG) { offsets[NSEG] = n; return; }
    int lo = 0, hi = n;
    while (lo < hi) {
        int mid = (lo + hi) >> 1;
        int val = is64 ? idx32[2 * mid] : idx32[mid];
        if (val < b) lo = mid + 1; else hi = mid;
    }
    offsets[b] = lo;
}

// ---------------- Kernel B: per-(segment,split) partial tiles ---------------
// grid = NSEG*spb blocks. Block (b,j) processes split j of segment b's nodes,
// accumulates a private 32x32 tile in LDS, writes it to part[] with PLAIN
// coalesced stores (no atomics anywhere in global memory).
__global__ __launch_bounds__(256) void ect_kernel(
    const float* __restrict__ x,       // [N,3]
    const float* __restrict__ v,       // [3,32]
    const float* __restrict__ lin,     // [32]
    const int*   __restrict__ scale_p, // [1]
    const int*   __restrict__ offsets, // [NSEG+1]
    float*       __restrict__ part,    // [NSEG*spb, 1024]
    int spb)
{
    __shared__ float acc[SSTEPS][TDIM];      // exact sigmoid window sums
    __shared__ float hist[SSTEPS + 1][TDIM]; // "+1 for all s>=s1" counts
    __shared__ float s_x[TILE * 3];
    __shared__ float s_lin[SSTEPS];
    __shared__ float s_v[3][TDIM];

    const int tid = threadIdx.x;
    const unsigned bx = blockIdx.x;
    const int b = bx / (unsigned)spb;
    const int j = bx % (unsigned)spb;

    for (int i = tid; i < SSTEPS * TDIM; i += 256) ((float*)acc)[i] = 0.f;
    for (int i = tid; i < (SSTEPS + 1) * TDIM; i += 256) ((float*)hist)[i] = 0.f;
    if (tid < SSTEPS) s_lin[tid] = lin[tid];
    if (tid < 3 * TDIM) ((float*)s_v)[tid] = v[tid];
    __syncthreads();

    const float scale = (float)scale_p[0];
    const float lin0 = s_lin[0];
    const float inv_step = 1.0f / (s_lin[1] - lin0);

    const int t = tid & 31;
    const int g = tid >> 5;               // 0..7 nodes in flight
    const float v0 = s_v[0][t], v1 = s_v[1][t], v2 = s_v[2][t];

    const int start = offsets[b], end = offsets[b + 1];
    const int cnt = end - start;
    const int chunk = (cnt + spb - 1) / spb;
    const int r0 = start + j * chunk;
    const int r1 = min(r0 + chunk, end);

    for (int base = r0; base < r1; base += TILE) {      // bounds block-uniform
        const int tc = min(TILE, r1 - base);
        __syncthreads();                                 // protect s_x reuse
        for (int i = tid; i < tc * 3; i += 256) s_x[i] = x[(size_t)base * 3 + i];
        __syncthreads();

        for (int k = g; k < tc; k += 8) {
            const float x0 = s_x[k * 3 + 0];
            const float x1 = s_x[k * 3 + 1];
            const float x2 = s_x[k * 3 + 2];
            const float nh = x0 * v0 + x1 * v1 + x2 * v2;

            float u = (nh - lin0) * inv_step;
            u = fminf(fmaxf(u, -8.0f), 48.0f);
            const int s_lo = (int)floorf(u);

            // exact sigmoids only at the two bracketing lin points;
            // sigmoid saturates to 0/1 exactly (fp32) everywhere else.
            if (s_lo >= 0 && s_lo < SSTEPS) {
                const float z = scale * (s_lin[s_lo] - nh);
                atomicAdd(&acc[s_lo][t], 1.0f / (1.0f + __expf(-z)));
            }
            const int c1 = s_lo + 1;
            if (c1 >= 0 && c1 < SSTEPS) {
                const float z = scale * (s_lin[c1] - nh);
                atomicAdd(&acc[c1][t], 1.0f / (1.0f + __expf(-z)));
            }
            int s1 = s_lo + 2;
            if (s1 < 0) s1 = 0;
            if (s1 < SSTEPS) atomicAdd(&hist[s1][t], 1.0f);
        }
    }
    __syncthreads();

    // prefix-sum hist over s per t
    if (tid < TDIM) {
        float run = 0.f;
        for (int s = 0; s < SSTEPS; ++s) {
            run += hist[s][tid];
            hist[s][tid] = run;
        }
    }
    __syncthreads();

    float* pb = part + (size_t)bx * (SSTEPS * TDIM);
    for (int i = tid; i < SSTEPS * TDIM; i += 256) {
        const int s = i >> 5, tt = i & 31;
        pb[i] = acc[s][tt] + hist[s][tt];    // plain store, no atomic
    }
}

// ---------------- Kernel C: reduce spb partials per segment -----------------
__global__ __launch_bounds__(256) void reduce_kernel(
    const float* __restrict__ part, float* __restrict__ out, int spb)
{
    const int b = blockIdx.x;
    for (int i = threadIdx.x; i < SSTEPS * TDIM; i += 256) {
        float s = 0.f;
        const float* p = part + (size_t)b * spb * (SSTEPS * TDIM) + i;
        for (int j = 0; j < spb; ++j) s += p[(size_t)j * (SSTEPS * TDIM)];
        out[(size_t)b * (SSTEPS * TDIM) + i] = s;       // plain store
    }
}

extern "C" void kernel_launch(void* const* d_in, const int* in_sizes, int n_in,
                              void* d_out, int out_size, void* d_ws, size_t ws_size,
                              hipStream_t stream) {
    const float* x     = (const float*)d_in[0];
    const int*   index = (const int*)d_in[1];
    const float* v     = (const float*)d_in[2];
    const float* lin   = (const float*)d_in[3];
    const int*   scale = (const int*)d_in[4];
    float* out = (float*)d_out;
    const int N = in_sizes[0] / 3;   // x is [N,3]

    int*   offsets = (int*)d_ws;                      // [NSEG+1]
    float* part    = (float*)((char*)d_ws + 2048);    // [NSEG*spb, 1024]

    int spb = 8;
    while (spb > 1 &&
           2048 + (size_t)NSEG * spb * SSTEPS * TDIM * sizeof(float) > ws_size)
        spb >>= 1;

    seg_offsets_kernel<<<1, 256, 0, stream>>>(index, N, offsets);
    ect_kernel<<<NSEG * spb, 256, 0, stream>>>(x, v, lin, scale, offsets, part, spb);
    reduce_kernel<<<NSEG, 256, 0, stream>>>(part, out, spb);
}

// Round 4
// 100.058 us; speedup vs baseline: 1.4416x; 1.4416x over previous
//
#include <hip/hip_runtime.h>

#define NSEG 128
#define SSTEPS 32
#define TDIM 32
#define TILE 256          // nodes staged to LDS per tile
#define NG 8              // banked accumulator copies (one per half-wave)

// ---------------- Kernel A: segment offsets via binary search ---------------
__global__ void seg_offsets_kernel(const int* __restrict__ idx32, int n,
                                   int* __restrict__ offsets) {
    int b = threadIdx.x;
    if (b > NSEG) return;
    bool is64 = (idx32[n - 1] == 0);   // int64 high word of last element
    if (b == NSEG) { offsets[NSEG] = n; return; }
    int lo = 0, hi = n;
    while (lo < hi) {
        int mid = (lo + hi) >> 1;
        int val = is64 ? idx32[2 * mid] : idx32[mid];
        if (val < b) lo = mid + 1; else hi = mid;
    }
    offsets[b] = lo;
}

// ---------------- Kernel B: per-(segment,split) partial tiles ---------------
// NO LDS atomics: thread (t = tid&31, g = tid>>5) exclusively owns
// acc[g][*][t] and hist[g][*][t] -> plain read-modify-write.
__global__ __launch_bounds__(256) void ect_kernel(
    const float* __restrict__ x,       // [N,3]
    const float* __restrict__ v,       // [3,32]
    const float* __restrict__ lin,     // [32]
    const int*   __restrict__ scale_p, // [1]
    const int*   __restrict__ offsets, // [NSEG+1]
    float*       __restrict__ part,    // [NSEG*spb, 1024]
    int spb)
{
    __shared__ float acc[NG][SSTEPS][TDIM];   // exact sigmoid sums (banked)
    __shared__ float hist[NG][SSTEPS][TDIM];  // step-start counts (banked)
    __shared__ float s_x[TILE * 3];
    __shared__ float s_lin[SSTEPS];
    __shared__ float s_v[3][TDIM];

    const int tid = threadIdx.x;
    const unsigned bx = blockIdx.x;
    const int b = bx / (unsigned)spb;
    const int j = bx % (unsigned)spb;

    for (int i = tid; i < NG * SSTEPS * TDIM; i += 256) {
        ((float*)acc)[i] = 0.f;
        ((float*)hist)[i] = 0.f;
    }
    if (tid < SSTEPS) s_lin[tid] = lin[tid];
    if (tid < 3 * TDIM) ((float*)s_v)[tid] = v[tid];
    __syncthreads();

    const float scale = (float)scale_p[0];
    const float lin0 = s_lin[0];
    const float step = s_lin[1] - lin0;
    const float inv_step = 1.0f / step;

    const int t = tid & 31;
    const int g = tid >> 5;               // 0..7, exclusive accumulator copy
    const float v0 = s_v[0][t], v1 = s_v[1][t], v2 = s_v[2][t];

    float* accg  = &acc[g][0][t];         // stride 32 floats over s
    float* histg = &hist[g][0][t];

    const int start = offsets[b], end = offsets[b + 1];
    const int cnt = end - start;
    const int chunk = (cnt + spb - 1) / spb;
    const int r0 = start + j * chunk;
    const int r1 = min(r0 + chunk, end);

    for (int base = r0; base < r1; base += TILE) {   // block-uniform bounds
        const int tc = min(TILE, r1 - base);
        __syncthreads();
        for (int i = tid; i < tc * 3; i += 256) s_x[i] = x[(size_t)base * 3 + i];
        __syncthreads();

        for (int k = g; k < tc; k += 8) {
            const float x0 = s_x[k * 3 + 0];
            const float x1 = s_x[k * 3 + 1];
            const float x2 = s_x[k * 3 + 2];
            const float nh = x0 * v0 + x1 * v1 + x2 * v2;

            float u = (nh - lin0) * inv_step;
            u = fminf(fmaxf(u, -8.0f), 48.0f);
            const int s_lo = (int)floorf(u);

            // exact sigmoids only at the two bracketing lin points;
            // sigmoid saturates to exactly 0/1 (fp32) everywhere else.
            if (s_lo >= 0 && s_lo < SSTEPS) {
                const float lin_s = fmaf((float)s_lo, step, lin0);
                const float z = scale * (lin_s - nh);
                accg[s_lo * 32] += 1.0f / (1.0f + __expf(-z));   // plain RMW
            }
            const int c1 = s_lo + 1;
            if (c1 >= 0 && c1 < SSTEPS) {
                const float lin_s = fmaf((float)c1, step, lin0);
                const float z = scale * (lin_s - nh);
                accg[c1 * 32] += 1.0f / (1.0f + __expf(-z));     // plain RMW
            }
            int s1 = s_lo + 2;
            if (s1 < 0) s1 = 0;
            if (s1 < SSTEPS) histg[s1 * 32] += 1.0f;             // plain RMW
        }
    }
    __syncthreads();

    // fold the NG banked copies into copy 0
    for (int c = tid; c < SSTEPS * TDIM; c += 256) {
        float sa = 0.f, sh = 0.f;
        for (int gg = 0; gg < NG; ++gg) {
            sa += ((float*)acc)[gg * 1024 + c];
            sh += ((float*)hist)[gg * 1024 + c];
        }
        ((float*)acc)[c] = sa;
        ((float*)hist)[c] = sh;
    }
    __syncthreads();

    // prefix-sum hist over s per t, add into acc[0]
    if (tid < TDIM) {
        float run = 0.f;
        for (int s = 0; s < SSTEPS; ++s) {
            run += hist[0][s][tid];
            acc[0][s][tid] += run;
        }
    }
    __syncthreads();

    float* pb = part + (size_t)bx * (SSTEPS * TDIM);
    for (int i = tid; i < SSTEPS * TDIM; i += 256)
        pb[i] = ((float*)acc)[i];          // plain coalesced store
}

// ---------------- Kernel C: reduce spb partials per segment -----------------
__global__ __launch_bounds__(256) void reduce_kernel(
    const float* __restrict__ part, float* __restrict__ out, int spb)
{
    const int b = blockIdx.x;
    for (int i = threadIdx.x; i < SSTEPS * TDIM; i += 256) {
        float s = 0.f;
        const float* p = part + (size_t)b * spb * (SSTEPS * TDIM) + i;
        for (int j = 0; j < spb; ++j) s += p[(size_t)j * (SSTEPS * TDIM)];
        out[(size_t)b * (SSTEPS * TDIM) + i] = s;
    }
}

extern "C" void kernel_launch(void* const* d_in, const int* in_sizes, int n_in,
                              void* d_out, int out_size, void* d_ws, size_t ws_size,
                              hipStream_t stream) {
    const float* x     = (const float*)d_in[0];
    const int*   index = (const int*)d_in[1];
    const float* v     = (const float*)d_in[2];
    const float* lin   = (const float*)d_in[3];
    const int*   scale = (const int*)d_in[4];
    float* out = (float*)d_out;
    const int N = in_sizes[0] / 3;   // x is [N,3]

    int*   offsets = (int*)d_ws;                      // [NSEG+1]
    float* part    = (float*)((char*)d_ws + 2048);    // [NSEG*spb, 1024]

    int spb = 8;
    while (spb > 1 &&
           2048 + (size_t)NSEG * spb * SSTEPS * TDIM * sizeof(float) > ws_size)
        spb >>= 1;

    seg_offsets_kernel<<<1, 256, 0, stream>>>(index, N, offsets);
    ect_kernel<<<NSEG * spb, 256, 0, stream>>>(x, v, lin, scale, offsets, part, spb);
    reduce_kernel<<<NSEG, 256, 0, stream>>>(part, out, spb);
}

// Round 5
// 86.871 us; speedup vs baseline: 1.6604x; 1.1518x over previous
//
#include <hip/hip_runtime.h>

#define NSEG 128
#define SSTEPS 32
#define TDIM 32
#define NG 8              // banked accumulator copies = blockDim/32
#define DROWS 34          // SSTEPS + 2 clamp rows (rows 32,33 discarded)
#define SPB 8             // splits per segment

// ---------------- Kernel B: per-(segment,split) partial tiles ---------------
// Difference-domain accumulation: per node, d/ds of the sigmoid step profile
// has exactly 3 nonzero entries at s_lo..s_lo+2 summing to exactly 1.
// Thread (g=tid>>5, t=tid&31) exclusively owns d[g][*][t] -> plain RMW,
// single LDS round-trip per node via read3 / cascade / write3.
__global__ __launch_bounds__(256) void ect_kernel(
    const float* __restrict__ x,       // [N,3]
    const int*   __restrict__ idx,     // [N] int32 or int64 (detected)
    const float* __restrict__ v,       // [3,32]
    const float* __restrict__ lin,     // [32]
    const int*   __restrict__ scale_p, // [1]
    float*       __restrict__ part,    // [NSEG*SPB, 1024]
    int N)
{
    __shared__ float d[NG][DROWS][TDIM];   // 34.8 KB total
    __shared__ int s_bounds[2];

    const int tid = threadIdx.x;
    const unsigned bx = blockIdx.x;
    const int b = bx >> 3;            // segment
    const int j = bx & (SPB - 1);     // split

    // inline segment-boundary binary search (lanes 0,1)
    if (tid < 2) {
        const bool is64 = (idx[N - 1] == 0);
        const int target = b + tid;
        int lo = 0, hi = N;
        while (lo < hi) {
            int mid = (lo + hi) >> 1;
            int val = is64 ? idx[2 * mid] : idx[mid];
            if (val < target) lo = mid + 1; else hi = mid;
        }
        s_bounds[tid] = lo;
    }
    for (int i = tid; i < NG * DROWS * TDIM; i += 256) ((float*)d)[i] = 0.f;

    const float lin0 = lin[0];                 // uniform -> s_load
    const float step = lin[1] - lin0;
    const float inv_step = 1.0f / step;
    const float scale = (float)scale_p[0];
    const float zstep = scale * step;          // ~35.5

    const int t = tid & 31;
    const int g = tid >> 5;
    const float v0 = v[t], v1 = v[TDIM + t], v2 = v[2 * TDIM + t];
    float* dg = &d[g][0][t];                   // row stride = 32 floats

    __syncthreads();

    const int start = s_bounds[0], end = s_bounds[1];
    const int cnt = end - start;
    const int chunk = (cnt + SPB - 1) / SPB;
    const int r0 = start + j * chunk;
    const int r1 = min(r0 + chunk, end);

    for (int k = r0 + g; k < r1; k += NG) {
        const float x0 = x[k * 3 + 0];
        const float x1 = x[k * 3 + 1];
        const float x2 = x[k * 3 + 2];
        const float nh = fmaf(x0, v0, fmaf(x1, v1, x2 * v2));

        float u = (nh - lin0) * inv_step;
        u = fminf(fmaxf(u, -8.0f), 48.0f);
        const int s_lo = (int)floorf(u);

        // z0 = scale*(lin[s_lo]-nh) in (-35.5, 0]; z1 = z0 + zstep in [0, 35.5)
        const float z0 = scale * (fmaf((float)s_lo, step, lin0) - nh);
        const float sig0 = 1.0f / (1.0f + __expf(-z0));        // f(s_lo)
        const float sig1c = 1.0f / (1.0f + __expf(z0 + zstep)); // 1 - f(s_lo+1)

        float w0 = sig0;
        float w1 = 1.0f - sig0 - sig1c;
        float w2 = sig1c;                       // w0+w1+w2 == 1 exactly

        const int i0 = min(max(s_lo,     0), DROWS - 1);
        const int i1 = min(max(s_lo + 1, 0), DROWS - 1);
        const int i2 = min(max(s_lo + 2, 0), DROWS - 1);

        // one LDS round-trip; cascade handles clamp-aliased rows
        const float a0 = dg[i0 * 32];
        const float a1 = dg[i1 * 32];
        const float a2 = dg[i2 * 32];
        if (i1 == i0) w1 += w0;
        if (i2 == i1) w2 += w1;
        dg[i0 * 32] = a0 + w0;
        dg[i1 * 32] = a1 + w1;
        dg[i2 * 32] = a2 + w2;                  // in-order: last write wins
    }
    __syncthreads();

    // fold NG banked copies into copy 0 (rows 0..31 only)
    for (int i = tid; i < SSTEPS * TDIM; i += 256) {
        const int s = i >> 5, tt = i & 31;
        float sum = 0.f;
        #pragma unroll
        for (int gg = 0; gg < NG; ++gg) sum += d[gg][s][tt];
        d[0][s][tt] = sum;
    }
    __syncthreads();

    // prefix-sum diffs over s per t (batched reads -> reg prefix -> writes)
    if (tid < TDIM) {
        float r[SSTEPS];
        #pragma unroll
        for (int s = 0; s < SSTEPS; ++s) r[s] = d[0][s][tid];
        float run = 0.f;
        #pragma unroll
        for (int s = 0; s < SSTEPS; ++s) { run += r[s]; d[0][s][tid] = run; }
    }
    __syncthreads();

    float* pb = part + (size_t)bx * (SSTEPS * TDIM);
    for (int i = tid; i < SSTEPS * TDIM; i += 256)
        pb[i] = ((float*)d)[i];                 // plain coalesced store
}

// ---------------- Kernel C: reduce SPB partials per segment -----------------
__global__ __launch_bounds__(256) void reduce_kernel(
    const float* __restrict__ part, float* __restrict__ out)
{
    const int b = blockIdx.x;
    for (int i = threadIdx.x; i < SSTEPS * TDIM; i += 256) {
        float s = 0.f;
        const float* p = part + (size_t)b * SPB * (SSTEPS * TDIM) + i;
        #pragma unroll
        for (int j = 0; j < SPB; ++j) s += p[(size_t)j * (SSTEPS * TDIM)];
        out[(size_t)b * (SSTEPS * TDIM) + i] = s;
    }
}

extern "C" void kernel_launch(void* const* d_in, const int* in_sizes, int n_in,
                              void* d_out, int out_size, void* d_ws, size_t ws_size,
                              hipStream_t stream) {
    const float* x     = (const float*)d_in[0];
    const int*   index = (const int*)d_in[1];
    const float* v     = (const float*)d_in[2];
    const float* lin   = (const float*)d_in[3];
    const int*   scale = (const int*)d_in[4];
    float* out = (float*)d_out;
    const int N = in_sizes[0] / 3;   // x is [N,3]

    float* part = (float*)d_ws;      // [NSEG*SPB, 1024] = 4 MB

    ect_kernel<<<NSEG * SPB, 256, 0, stream>>>(x, index, v, lin, scale, part, N);
    reduce_kernel<<<NSEG, 256, 0, stream>>>(part, out);
}

// Round 6
// 83.694 us; speedup vs baseline: 1.7234x; 1.0380x over previous
//
#include <hip/hip_runtime.h>

#define NSEG 128
#define SSTEPS 32
#define TDIM 32
#define NG 8               // banked accumulator copies = blockDim/32
#define DROWS 37           // rows s_lo..s_lo+2 with s_lo in [-2,34] -> [0,36]; s>=32 junk
#define SPB 8              // splits per segment
#define CSTR (DROWS * TDIM)   // 1184 floats per banked copy (16B-aligned)

// ---------------- Kernel B: per-(segment,split) partial tiles ---------------
// Difference-domain accumulation: per (node,t), d/ds of the sigmoid step
// profile has exactly 3 nonzero entries at s_lo..s_lo+2 summing to exactly 1.
// Thread (g=tid>>5, t=tid&31) exclusively owns d[g][*][t] -> plain RMW.
// Low-side clamp folds far-left mass into row 0 (exact: weights telescope);
// high side lands in junk rows 32..36, discarded by the prefix.
__global__ __launch_bounds__(256) void ect_kernel(
    const float* __restrict__ x,       // [N,3]
    const int*   __restrict__ idx,     // [N] int32 or int64 (detected)
    const float* __restrict__ v,       // [3,32]
    const float* __restrict__ lin,     // [32]
    const int*   __restrict__ scale_p, // [1]
    float*       __restrict__ part,    // [NSEG*SPB, 1024]
    int N)
{
    __shared__ float d[NG][DROWS][TDIM];   // 37.9 KB
    __shared__ int s_bounds[2];

    const int tid = threadIdx.x;
    const unsigned bx = blockIdx.x;
    const int b = bx >> 3;            // segment
    const int j = bx & (SPB - 1);     // split

    // inline segment-boundary binary search (lanes 0,1)
    if (tid < 2) {
        const bool is64 = (idx[N - 1] == 0);
        const int target = b + tid;
        int lo = 0, hi = N;
        while (lo < hi) {
            int mid = (lo + hi) >> 1;
            int val = is64 ? idx[2 * mid] : idx[mid];
            if (val < target) lo = mid + 1; else hi = mid;
        }
        s_bounds[tid] = lo;
    }
    // zero-init banked accumulators (float4)
    {
        float4* dz = (float4*)d;
        for (int i = tid; i < NG * CSTR / 4; i += 256)
            dz[i] = make_float4(0.f, 0.f, 0.f, 0.f);
    }

    const float lin0 = lin[0];
    const float step = lin[1] - lin0;
    const float inv_step = 1.0f / step;
    const float scale = (float)scale_p[0];
    const float zstep = scale * step;          // ~35.48
    const float C = __expf(zstep);             // e^{zstep}, ~2.6e15 (finite)

    const int t = tid & 31;
    const int g = tid >> 5;
    const float v0 = v[t], v1 = v[TDIM + t], v2 = v[2 * TDIM + t];
    float* dg = &d[g][0][t];                   // row stride = 32 floats

    __syncthreads();

    const int start = s_bounds[0], end = s_bounds[1];
    const int cnt = end - start;
    const int chunk = (cnt + SPB - 1) / SPB;
    const int r0 = start + j * chunk;
    const int r1 = min(r0 + chunk, end);

    for (int k = r0 + g; k < r1; k += NG) {
        const float x0 = x[k * 3 + 0];
        const float x1 = x[k * 3 + 1];
        const float x2 = x[k * 3 + 2];
        const float nh = fmaf(x0, v0, fmaf(x1, v1, x2 * v2));

        float u = (nh - lin0) * inv_step;
        u = fminf(fmaxf(u, -2.0f), 34.0f);
        const float sf = floorf(u);
        const int s_lo = (int)sf;

        // z0 = -zstep*frac(u) in (-35.5, 0]; single exp serves both sigmoids
        const float E = __expf((sf - u) * zstep);     // e^{z0} in (0,1]
        const float sig0  = E / (1.0f + E);           // sigma(z0)
        const float sig1c = 1.0f / (1.0f + E * C);    // 1 - sigma(z0+zstep)

        float w0 = sig0;
        float w1 = 1.0f - sig0 - sig1c;
        float w2 = sig1c;                             // w0+w1+w2 == 1

        const int i0 = max(s_lo, 0);
        const int i1 = max(s_lo + 1, 0);
        const int i2 = s_lo + 2;                      // >= 0 by clamp

        // one LDS round-trip; cascade handles clamp-aliased rows
        const float a0 = dg[i0 * 32];
        const float a1 = dg[i1 * 32];
        const float a2 = dg[i2 * 32];
        if (i1 == i0) w1 += w0;
        if (i2 == i1) w2 += w1;
        dg[i0 * 32] = a0 + w0;
        dg[i1 * 32] = a1 + w1;
        dg[i2 * 32] = a2 + w2;                        // in-order: last wins
    }
    __syncthreads();

    // fold NG banked copies into copy 0, rows 0..31 (float4: 8 b128 reads)
    {
        const float* base = (const float*)d;
        float4 sum = make_float4(0.f, 0.f, 0.f, 0.f);
        #pragma unroll
        for (int gg = 0; gg < NG; ++gg) {
            const float4 vq = ((const float4*)(base + gg * CSTR))[tid];
            sum.x += vq.x; sum.y += vq.y; sum.z += vq.z; sum.w += vq.w;
        }
        ((float4*)d)[tid] = sum;     // each thread RMWs only its own 4 cells
    }
    __syncthreads();

    // prefix-sum diffs over s per t, store partial tile directly (coalesced)
    if (tid < TDIM) {
        const float* df = (const float*)d;
        float* pb = part + (size_t)bx * (SSTEPS * TDIM);
        float run = 0.f;
        #pragma unroll
        for (int s = 0; s < SSTEPS; ++s) {
            run += df[s * 32 + tid];
            pb[s * 32 + tid] = run;
        }
    }
}

// ---------------- Kernel C: reduce SPB partials per segment (float4) --------
__global__ __launch_bounds__(256) void reduce_kernel(
    const float4* __restrict__ part, float4* __restrict__ out)
{
    const int b = blockIdx.x;
    const int q = threadIdx.x;               // 256 float4 cells per segment
    float4 s = make_float4(0.f, 0.f, 0.f, 0.f);
    #pragma unroll
    for (int j = 0; j < SPB; ++j) {
        const float4 p = part[(size_t)(b * SPB + j) * 256 + q];
        s.x += p.x; s.y += p.y; s.z += p.z; s.w += p.w;
    }
    out[(size_t)b * 256 + q] = s;
}

extern "C" void kernel_launch(void* const* d_in, const int* in_sizes, int n_in,
                              void* d_out, int out_size, void* d_ws, size_t ws_size,
                              hipStream_t stream) {
    const float* x     = (const float*)d_in[0];
    const int*   index = (const int*)d_in[1];
    const float* v     = (const float*)d_in[2];
    const float* lin   = (const float*)d_in[3];
    const int*   scale = (const int*)d_in[4];
    float* out = (float*)d_out;
    const int N = in_sizes[0] / 3;   // x is [N,3]

    float* part = (float*)d_ws;      // [NSEG*SPB, 1024] = 4 MB

    ect_kernel<<<NSEG * SPB, 256, 0, stream>>>(x, index, v, lin, scale, part, N);
    reduce_kernel<<<NSEG, 256, 0, stream>>>((const float4*)part, (float4*)out);
}

// Round 7
// 79.707 us; speedup vs baseline: 1.8096x; 1.0500x over previous
//
#include <hip/hip_runtime.h>

#define NSEG 128
#define SSTEPS 32
#define TDIM 32
#define NG 8               // banked accumulator copies = blockDim/32
#define DROWS 37           // rows base..base+2, base in [0,34] -> [0,36]; s>=32 junk
#define SPB 8              // splits per segment
#define CSTR (DROWS * TDIM)   // 1184 floats per banked copy

// ---------------- Kernel B: per-(segment,split) partial tiles ---------------
// Difference-domain accumulation: per (node,t), d/ds of the sigmoid step
// profile has exactly 3 nonzero entries at consecutive rows summing to 1.
// Thread (g=tid>>5, t=tid&31) exclusively owns d[g][*][t] -> plain RMW with
// provably-consecutive rows (ds_read2/ds_write2 mergeable).
__global__ __launch_bounds__(256) void ect_kernel(
    const float* __restrict__ x,       // [N,3]
    const int*   __restrict__ idx,     // [N] int32 or int64 (N even; detected)
    const float* __restrict__ v,       // [3,32]
    const float* __restrict__ lin,     // [32]
    const int*   __restrict__ scale_p, // [1]
    float*       __restrict__ part,    // [NSEG*SPB, 1024]
    int N)
{
    __shared__ float d[NG][DROWS][TDIM];   // 37.9 KB
    __shared__ int s_bounds[2];

    const int tid = threadIdx.x;
    const unsigned bx = blockIdx.x;
    const int b = bx >> 3;            // segment
    const int j = bx & (SPB - 1);     // split

    // ---- wave-parallel segment-boundary search (wave 0) ----
    // halves: lanes 0-31 -> target b, lanes 32-63 -> target b+1
    if (tid < 64) {
        const int L = tid & 31;
        const int h = tid >> 5;
        const int target = b + h;
        const int g0 = (int)(((long long)target * N) >> 7);  // *N/128 guess

        // round 0: is64 detect + speculative int32 window (parallel loads)
        const int hi_last = idx[N - 1];          // ==0 iff int64 (N even)
        int p1 = g0 - 1024 + 64 * L;
        int pc1 = min(max(p1, 0), N - 1);
        int val32 = idx[pc1];
        const bool is64 = (hi_last == 0);
        // round 1b (int64 only): reload window at doubled addresses
        int val = is64 ? idx[2 * pc1] : val32;

        bool pred1 = (p1 < 0) ? true : ((p1 >= N) ? false : (val < target));
        unsigned long long m1 = __ballot(pred1);
        unsigned hm1 = (unsigned)(m1 >> (h * 32));

        int boundary;
        if (hm1 == 0u || hm1 == 0xFFFFFFFFu) {
            // window miss (|deviation| > ~1000) -> serial fallback, lane L==0
            if (L == 0) {
                int lo = 0, hi = N;
                while (lo < hi) {
                    int mid = (lo + hi) >> 1;
                    int vv = is64 ? idx[2 * mid] : idx[mid];
                    if (vv < target) lo = mid + 1; else hi = mid;
                }
                s_bounds[h] = lo;
            }
        } else {
            const int A = g0 - 1024 + 64 * (31 - __builtin_clz(hm1));
            // round 2: stride-2 probes of (A, A+64]
            int p2 = A + 1 + 2 * L;
            int pc2 = min(max(p2, 0), N - 1);
            int v2 = is64 ? idx[2 * pc2] : idx[pc2];
            bool pred2 = (p2 < 0) ? true : ((p2 >= N) ? false : (v2 < target));
            unsigned long long m2 = __ballot(pred2);
            unsigned hm2 = (unsigned)(m2 >> (h * 32));
            const int B = hm2 ? (A + 1 + 2 * (31 - __builtin_clz(hm2))) : A;
            // round 3: single probe at B+1 (broadcast load)
            int p3 = B + 1;
            int pc3 = min(p3, N - 1);
            int v3 = is64 ? idx[2 * pc3] : idx[pc3];
            bool pred3 = (p3 >= N) ? false : (v3 < target);
            boundary = pred3 ? (B + 2) : (B + 1);
            if (L == 0) s_bounds[h] = boundary;
        }
    }
    // zero-init banked accumulators (float4)
    {
        float4* dz = (float4*)d;
        for (int i = tid; i < NG * CSTR / 4; i += 256)
            dz[i] = make_float4(0.f, 0.f, 0.f, 0.f);
    }

    const float lin0 = lin[0];
    const float step = lin[1] - lin0;
    const float inv_step = 1.0f / step;
    const float scale = (float)scale_p[0];
    const float zstep = scale * step;          // ~35.48
    const float C = __expf(zstep);             // e^{zstep}, finite

    const int t = tid & 31;
    const int g = tid >> 5;
    const float v0 = v[t], v1 = v[TDIM + t], v2 = v[2 * TDIM + t];
    float* dg = &d[g][0][t];                   // row stride = 32 floats

    __syncthreads();

    const int start = s_bounds[0], end = s_bounds[1];
    const int cnt = end - start;
    const int chunk = (cnt + SPB - 1) / SPB;
    const int r0 = start + j * chunk;
    const int r1 = min(r0 + chunk, end);

    for (int k = r0 + g; k < r1; k += NG) {
        const float x0 = x[k * 3 + 0];
        const float x1 = x[k * 3 + 1];
        const float x2 = x[k * 3 + 2];
        const float nh = fmaf(x0, v0, fmaf(x1, v1, x2 * v2));

        float u = (nh - lin0) * inv_step;
        u = fminf(fmaxf(u, -2.0f), 34.0f);
        const float sf = floorf(u);
        const int s_lo = (int)sf;

        // single exp serves both bracketing sigmoids
        const float E = __expf((sf - u) * zstep);     // e^{z0} in (0,1]
        const float sig0  = E / (1.0f + E);
        const float sig1c = 1.0f / (1.0f + E * C);

        float w0 = sig0;
        float w1 = 1.0f - sig0 - sig1c;
        float w2 = sig1c;                             // sums to 1

        // left clamp by weight shift -> rows always consecutive
        if (s_lo < 0) {
            if (s_lo == -1) { w0 = w0 + w1; w1 = w2; w2 = 0.f; }
            else            { w0 = 1.0f;    w1 = 0.f; w2 = 0.f; }
        }
        const int base = max(s_lo, 0);                // 0..34

        float* p = dg + base * 32;
        const float a0 = p[0];                        // ds_read2 + ds_read
        const float a1 = p[32];
        const float a2 = p[64];
        p[0]  = a0 + w0;                              // ds_write2 + ds_write
        p[32] = a1 + w1;
        p[64] = a2 + w2;
    }
    __syncthreads();

    // fold NG banked copies into copy 0, rows 0..31 (float4 b128 reads)
    {
        const float* basep = (const float*)d;
        float4 sum = make_float4(0.f, 0.f, 0.f, 0.f);
        #pragma unroll
        for (int gg = 0; gg < NG; ++gg) {
            const float4 vq = ((const float4*)(basep + gg * CSTR))[tid];
            sum.x += vq.x; sum.y += vq.y; sum.z += vq.z; sum.w += vq.w;
        }
        ((float4*)d)[tid] = sum;
    }
    __syncthreads();

    // prefix-sum diffs over s per t, store partial tile directly (coalesced)
    if (tid < TDIM) {
        const float* df = (const float*)d;
        float* pb = part + (size_t)bx * (SSTEPS * TDIM);
        float run = 0.f;
        #pragma unroll
        for (int s = 0; s < SSTEPS; ++s) {
            run += df[s * 32 + tid];
            pb[s * 32 + tid] = run;
        }
    }
}

// ---------------- Kernel C: reduce SPB partials per segment (float4) --------
__global__ __launch_bounds__(256) void reduce_kernel(
    const float4* __restrict__ part, float4* __restrict__ out)
{
    const int b = blockIdx.x;
    const int q = threadIdx.x;               // 256 float4 cells per segment
    float4 s = make_float4(0.f, 0.f, 0.f, 0.f);
    #pragma unroll
    for (int j = 0; j < SPB; ++j) {
        const float4 p = part[(size_t)(b * SPB + j) * 256 + q];
        s.x += p.x; s.y += p.y; s.z += p.z; s.w += p.w;
    }
    out[(size_t)b * 256 + q] = s;
}

extern "C" void kernel_launch(void* const* d_in, const int* in_sizes, int n_in,
                              void* d_out, int out_size, void* d_ws, size_t ws_size,
                              hipStream_t stream) {
    const float* x     = (const float*)d_in[0];
    const int*   index = (const int*)d_in[1];
    const float* v     = (const float*)d_in[2];
    const float* lin   = (const float*)d_in[3];
    const int*   scale = (const int*)d_in[4];
    float* out = (float*)d_out;
    const int N = in_sizes[0] / 3;   // x is [N,3]

    float* part = (float*)d_ws;      // [NSEG*SPB, 1024] = 4 MB

    ect_kernel<<<NSEG * SPB, 256, 0, stream>>>(x, index, v, lin, scale, part, N);
    reduce_kernel<<<NSEG, 256, 0, stream>>>((const float4*)part, (float4*)out);
}

// Round 8
// 78.473 us; speedup vs baseline: 1.8381x; 1.0157x over previous
//
#include <hip/hip_runtime.h>

#define NSEG 128
#define SSTEPS 32
#define TDIM 32
#define NG 8               // banked accumulator copies = blockDim/32
#define DROWS 37           // rows base..base+2, base in [0,34]; s>=32 junk
#define SPB 8              // splits per segment
#define CSTR (DROWS * TDIM)   // 1184 floats per banked copy

// ---------------- Kernel: per-(segment,split) tiles, fused epilogue ---------
// Difference-domain accumulation: per (node,t), d/ds of the sigmoid step
// profile has exactly 3 nonzero entries at consecutive rows summing to 1.
// Thread (g=tid>>5, t=tid&31) exclusively owns d[g][*][t] -> plain RMW.
// Epilogue: fold banked copies, prefix over s, atomicAdd into out directly.
__global__ __launch_bounds__(256) void ect_kernel(
    const float* __restrict__ x,       // [N,3]
    const int*   __restrict__ idx,     // [N] int32 or int64 (N even; detected)
    const float* __restrict__ v,       // [3,32]
    const float* __restrict__ lin,     // [32]
    const int*   __restrict__ scale_p, // [1]
    float*       __restrict__ out,     // [NSEG,32,32], pre-zeroed
    int N)
{
    __shared__ float d[NG][DROWS][TDIM];   // 37.9 KB
    __shared__ int s_bounds[2];

    const int tid = threadIdx.x;
    const unsigned bx = blockIdx.x;
    const int b = bx >> 3;            // segment
    const int j = bx & (SPB - 1);     // split

    // ---- wave-parallel segment-boundary search (wave 0) ----
    // halves: lanes 0-31 -> target b, lanes 32-63 -> target b+1
    if (tid < 64) {
        const int L = tid & 31;
        const int h = tid >> 5;
        const int target = b + h;
        const int g0 = (int)(((long long)target * N) >> 7);  // *N/128 guess

        const int hi_last = idx[N - 1];          // ==0 iff int64 (N even)
        int p1 = g0 - 1024 + 64 * L;
        int pc1 = min(max(p1, 0), N - 1);
        int val32 = idx[pc1];
        const bool is64 = (hi_last == 0);
        int val = is64 ? idx[2 * pc1] : val32;

        bool pred1 = (p1 < 0) ? true : ((p1 >= N) ? false : (val < target));
        unsigned long long m1 = __ballot(pred1);
        unsigned hm1 = (unsigned)(m1 >> (h * 32));

        if (hm1 == 0u || hm1 == 0xFFFFFFFFu) {
            if (L == 0) {                       // rare fallback: serial search
                int lo = 0, hi = N;
                while (lo < hi) {
                    int mid = (lo + hi) >> 1;
                    int vv = is64 ? idx[2 * mid] : idx[mid];
                    if (vv < target) lo = mid + 1; else hi = mid;
                }
                s_bounds[h] = lo;
            }
        } else {
            const int A = g0 - 1024 + 64 * (31 - __builtin_clz(hm1));
            int p2 = A + 1 + 2 * L;
            int pc2 = min(max(p2, 0), N - 1);
            int v2 = is64 ? idx[2 * pc2] : idx[pc2];
            bool pred2 = (p2 < 0) ? true : ((p2 >= N) ? false : (v2 < target));
            unsigned long long m2 = __ballot(pred2);
            unsigned hm2 = (unsigned)(m2 >> (h * 32));
            const int B = hm2 ? (A + 1 + 2 * (31 - __builtin_clz(hm2))) : A;
            int p3 = B + 1;
            int pc3 = min(p3, N - 1);
            int v3 = is64 ? idx[2 * pc3] : idx[pc3];
            bool pred3 = (p3 >= N) ? false : (v3 < target);
            if (L == 0) s_bounds[h] = pred3 ? (B + 2) : (B + 1);
        }
    }
    // zero-init banked accumulators (float4)
    {
        float4* dz = (float4*)d;
        for (int i = tid; i < NG * CSTR / 4; i += 256)
            dz[i] = make_float4(0.f, 0.f, 0.f, 0.f);
    }

    const float lin0 = lin[0];
    const float step = lin[1] - lin0;
    const float inv_step = 1.0f / step;
    const float scale = (float)scale_p[0];
    const float zstep = scale * step;          // ~35.48
    const float C = __expf(zstep);             // e^{zstep}, finite

    const int t = tid & 31;
    const int g = tid >> 5;
    const float v0 = v[t], v1 = v[TDIM + t], v2 = v[2 * TDIM + t];
    float* dg = &d[g][0][t];                   // row stride = 32 floats

    __syncthreads();

    const int start = s_bounds[0], end = s_bounds[1];
    const int cnt = end - start;
    const int chunk = (cnt + SPB - 1) / SPB;
    const int r0 = start + j * chunk;
    const int r1 = min(r0 + chunk, end);

    for (int k = r0 + g; k < r1; k += NG) {
        const float x0 = x[k * 3 + 0];
        const float x1 = x[k * 3 + 1];
        const float x2 = x[k * 3 + 2];
        const float nh = fmaf(x0, v0, fmaf(x1, v1, x2 * v2));

        float u = (nh - lin0) * inv_step;
        u = fminf(fmaxf(u, -2.0f), 34.0f);
        const float sf = floorf(u);
        const int s_lo = (int)sf;

        // single exp serves both bracketing sigmoids
        const float E = __expf((sf - u) * zstep);     // e^{z0} in (0,1]
        const float sig0  = E / (1.0f + E);
        const float sig1c = 1.0f / (1.0f + E * C);

        float w0 = sig0;
        float w1 = 1.0f - sig0 - sig1c;
        float w2 = sig1c;                             // sums to 1

        // left clamp by weight shift -> rows always consecutive
        if (s_lo < 0) {
            if (s_lo == -1) { w0 = w0 + w1; w1 = w2; w2 = 0.f; }
            else            { w0 = 1.0f;    w1 = 0.f; w2 = 0.f; }
        }
        const int base = max(s_lo, 0);                // 0..34

        float* p = dg + base * 32;
        const float a0 = p[0];                        // ds_read2 + ds_read
        const float a1 = p[32];
        const float a2 = p[64];
        p[0]  = a0 + w0;                              // ds_write2 + ds_write
        p[32] = a1 + w1;
        p[64] = a2 + w2;
    }
    __syncthreads();

    // fold NG banked copies into copy 0, rows 0..31 (float4 b128 reads)
    {
        const float* basep = (const float*)d;
        float4 sum = make_float4(0.f, 0.f, 0.f, 0.f);
        #pragma unroll
        for (int gg = 0; gg < NG; ++gg) {
            const float4 vq = ((const float4*)(basep + gg * CSTR))[tid];
            sum.x += vq.x; sum.y += vq.y; sum.z += vq.z; sum.w += vq.w;
        }
        ((float4*)d)[tid] = sum;
    }
    __syncthreads();

    // prefix-sum diffs over s per t (32 threads), back into LDS
    if (tid < TDIM) {
        float* df = (float*)d;
        float run = 0.f;
        #pragma unroll
        for (int s = 0; s < SSTEPS; ++s) {
            run += df[s * 32 + tid];
            df[s * 32 + tid] = run;
        }
    }
    __syncthreads();

    // fused reduction: atomicAdd tile into out (coalesced, 4 cells/thread)
    {
        const float* df = (const float*)d;
        float* ob = out + (size_t)b * (SSTEPS * TDIM);
        #pragma unroll
        for (int q = 0; q < 4; ++q)
            atomicAdd(&ob[q * 256 + tid], df[q * 256 + tid]);
    }
}

extern "C" void kernel_launch(void* const* d_in, const int* in_sizes, int n_in,
                              void* d_out, int out_size, void* d_ws, size_t ws_size,
                              hipStream_t stream) {
    const float* x     = (const float*)d_in[0];
    const int*   index = (const int*)d_in[1];
    const float* v     = (const float*)d_in[2];
    const float* lin   = (const float*)d_in[3];
    const int*   scale = (const int*)d_in[4];
    float* out = (float*)d_out;
    const int N = in_sizes[0] / 3;   // x is [N,3]

    hipMemsetAsync(d_out, 0, (size_t)out_size * sizeof(float), stream);
    ect_kernel<<<NSEG * SPB, 256, 0, stream>>>(x, index, v, lin, scale, out, N);
}